// Round 10
// baseline (186.668 us; speedup 1.0000x reference)
//
#include <hip/hip_runtime.h>
#include <hip/hip_bf16.h>

// CondConv: B=32, CIN=128, COUT=256, K=3, E=8, H=W=64 -> out [32,256,62,62] fp32
// Pipeline: nhwc(+pool partials) -> route -> combine(bf16 cw) -> implicit-GEMM
//           MFMA conv: block 128 couts x 248 pos (4 output rows), 4 waves
//           (2M x 2N, per-wave 64x128: 64 MFMA / 24 ds_read per iter),
//           B RESIDENT in LDS per cin-half (48KB, staged 2x total),
//           A streamed via dbuf (16KB/iter), 2 blocks/CU, counted vmcnt,
//           XCD-local grid 1024 (no tail), full K-unroll.

#define CC_B    32
#define CC_CIN  128
#define CC_COUT 256
#define CC_NP   3844   // 62*62
#define CC_NT   18     // t = h*9 + t9 : h = cin-half (64), t9 = tap

typedef __attribute__((ext_vector_type(8))) short bf16x8;
typedef __attribute__((ext_vector_type(4))) float f32x4;

// ------------------------------------------------- NHWC cast + pool partials
__global__ void cc_nhwc(const float* __restrict__ x, __hip_bfloat16* __restrict__ xn,
                        float* __restrict__ psum) {
    const int b = blockIdx.x >> 6, y = blockIdx.x & 63;   // 2048 blocks
    __shared__ float lds[64 * 129];                        // [x][cin], +1 pad
    __shared__ float sred[256];
    const int t = threadIdx.x;                             // 256
    const float* src = x + (size_t)b * CC_CIN * 4096 + y * 64;
#pragma unroll
    for (int i = 0; i < 32; ++i) {
        const int idx = i * 256 + t;
        const int cin = idx >> 6, xx = idx & 63;
        lds[xx * 129 + cin] = src[(size_t)cin * 4096 + xx];
    }
    __syncthreads();
    __hip_bfloat16* dst = xn + ((size_t)b * 4096 + y * 64) * CC_CIN;
#pragma unroll
    for (int j = 0; j < 4; ++j) {
        const int cidx = j * 256 + t;                      // 1024 chunks of 8 cin
        const int xx = cidx >> 4, c8 = (cidx & 15) * 8;
        union { __hip_bfloat16 h[8]; uint4 v; } u;
#pragma unroll
        for (int jj = 0; jj < 8; ++jj) u.h[jj] = __float2bfloat16(lds[xx * 129 + c8 + jj]);
        *reinterpret_cast<uint4*>(dst + (size_t)xx * CC_CIN + c8) = u.v;
    }
    const int cin = t & 127, xh = (t >> 7) * 32;
    float s = 0.f;
#pragma unroll
    for (int xx = 0; xx < 32; ++xx) s += lds[(xh + xx) * 129 + cin];
    sred[t] = s;
    __syncthreads();
    if (t < 128) psum[((size_t)b * 64 + y) * CC_CIN + t] = sred[t] + sred[t + 128];
}

// ------------------------------------------------- route: reduce + softmax --
__global__ void cc_route(const float* __restrict__ psum,
                         const float* __restrict__ rw_w,
                         const float* __restrict__ rw_b,
                         float* __restrict__ rweights) {
    const int b = blockIdx.x, c = threadIdx.x;             // 32 blocks x 128
    __shared__ float pl[128];
    __shared__ float lg[8];
    const float* p = psum + (size_t)b * 64 * CC_CIN + c;
    float s = 0.f;
#pragma unroll 8
    for (int y = 0; y < 64; ++y) s += p[(size_t)y * CC_CIN];
    pl[c] = s * (1.f / 4096.f);
    __syncthreads();
    if (c < 8) {
        const float* w = rw_w + c * CC_CIN;
        float a = rw_b[c];
#pragma unroll 8
        for (int i = 0; i < CC_CIN; ++i) a += pl[i] * w[i];
        lg[c] = a;
    }
    __syncthreads();
    if (c == 0) {
        float m = lg[0];
#pragma unroll
        for (int e = 1; e < 8; ++e) m = fmaxf(m, lg[e]);
        float ex[8], sm = 0.f;
#pragma unroll
        for (int e = 0; e < 8; ++e) { ex[e] = __expf(lg[e] - m); sm += ex[e]; }
#pragma unroll
        for (int e = 0; e < 8; ++e) rweights[b * 8 + e] = ex[e] / sm;
    }
}

// -------------------------------------------------------------- combine -----
__global__ void cc_combine(const float* __restrict__ ew,
                           const float* __restrict__ rw,
                           __hip_bfloat16* __restrict__ cw) {
    const int t9 = blockIdx.x >> 8;            // 0..8
    const int cout = blockIdx.x & 255;
    const int cin = threadIdx.x;               // 128 threads
    __shared__ float rws[256];
    rws[cin] = rw[cin];
    rws[cin + 128] = rw[cin + 128];
    __syncthreads();
    float wv[8];
    const size_t base = ((size_t)cout * CC_CIN + cin) * 9 + t9;
#pragma unroll
    for (int e = 0; e < 8; ++e) wv[e] = ew[base + (size_t)e * (CC_COUT * CC_CIN * 9)];
#pragma unroll 4
    for (int b = 0; b < CC_B; ++b) {
        float acc = 0.f;
#pragma unroll
        for (int e = 0; e < 8; ++e) acc += rws[b * 8 + e] * wv[e];
        cw[(((size_t)b * 9 + t9) * CC_COUT + cout) * CC_CIN + cin] = __float2bfloat16(acc);
    }
}

// ----------------------------------------------------------------- conv -----
__device__ __forceinline__ void gload_lds16(const void* g, void* l) {
    __builtin_amdgcn_global_load_lds(
        (const __attribute__((address_space(1))) unsigned int*)g,
        (__attribute__((address_space(3))) unsigned int*)l, 16, 0, 0);
}

// grid 1024, block 256 (4 waves, 2M x 2N). Tile BM=128 x BN=248 (4 out rows),
// per-wave 64x128 (clamped to 248): acc[4][8], 64 MFMA / 24 ds_read per iter.
// LDS 80KB: A dbuf 2x16KB @0; B resident @32768: 48KB = [row=yy*64+x][64cin]
// (6 input rows), staged once per cin-half h (restage at t=9).
// Loop t=0..17 (h=t/9, t9=t%9), full unroll. Ledger: A-stage=4 loads;
//   open(t): vmcnt(4) [A(t+1) in flight] + barrier; frag reads + 64 MFMA;
//   close(t): lgkm0 + barrier; [t==8: issue Bres(1) x12 first]; stage A(t+2).
// Swizzle: slot s of 128B row r holds source chunk s^(r&7); B rows are x-major
// (row = yy*64+x => row&7 == x&7), read XOR keyed on (ox+kx)&7. [verified]
__global__ __launch_bounds__(256, 2) void cc_conv(
    const __hip_bfloat16* __restrict__ xn,   // [B][64][64][128]
    const __hip_bfloat16* __restrict__ cw,   // [B][9][256][128]
    float* __restrict__ out)                 // [B][256][3844]
{
    __shared__ __align__(16) char smem[81920];
    // ---- XCD-aware decode (bijective over 1024 = 8 xcd x 4 b x 16 nt x 2 mt)
    const int l   = blockIdx.x;
    const int xcd = l & 7, li = l >> 3;          // li in [0,128)
    const int b   = 4 * xcd + (li >> 5);
    const int r2  = li & 31;
    const int nt  = r2 >> 1, mt = r2 & 1;
    const int m0  = mt * 128;
    const int n0  = nt * 248;                    // output rows nt*4..nt*4+3
    const int y0  = nt * 4;                      // input rows y0..y0+5

    const int tid = threadIdx.x;
    const int wid = tid >> 6, lane = tid & 63;   // wid 0..3
    const int waveM = wid >> 1, waveN = wid & 1;

    f32x4 acc[4][8];
#pragma unroll
    for (int i = 0; i < 4; ++i)
#pragma unroll
        for (int j = 0; j < 8; ++j) acc[i][j] = (f32x4){0.f, 0.f, 0.f, 0.f};

    const int gsw = (lane & 7) ^ (lane >> 3);    // staging source-chunk swizzle
    const __hip_bfloat16* cwb = cw + (size_t)b * 9 * CC_COUT * CC_CIN;
    const __hip_bfloat16* xnb = xn + (size_t)b * 4096 * CC_CIN;

    // ---- A staging (4 issues/wave, rows wid*32+i*8+(l>>3), R9 pattern)
    int laOff[4];
#pragma unroll
    for (int i = 0; i < 4; ++i) {
        const int row = wid * 32 + i * 8 + (lane >> 3);
        laOff[i] = (m0 + row) * CC_CIN + gsw * 8;
    }
    auto stageA = [&](int t) {
        const int h = t / 9, t9 = t - 9 * h;
        const int aoff = t9 * (CC_COUT * CC_CIN) + h * 64;
        char* Ab = smem + (t & 1) * 16384 + wid * 4096;
#pragma unroll
        for (int i = 0; i < 4; ++i)
            gload_lds16(cwb + aoff + laOff[i], Ab + i * 1024);
    };

    // ---- B resident staging: 48KB = 384 rows x 128B; 12 issues/wave.
    // row = i*32 + wid*8 + (lane>>3); yy=row>>6, x=row&63; row&7 == (lane>>3)&7
    char* Bres = smem + 32768;
    auto stageB = [&](int h) {
#pragma unroll
        for (int i = 0; i < 12; ++i) {
            const int row = i * 32 + wid * 8 + (lane >> 3);
            const int yy = row >> 6, x = row & 63;
            int yin = y0 + yy; if (yin > 63) yin = 63;
            gload_lds16(xnb + ((size_t)yin * 64 + x) * CC_CIN + h * 64 + gsw * 8,
                        Bres + i * 4096 + wid * 1024);
        }
    };

    const int rl = lane & 15, q = lane >> 4;

    // per-lane B column decode (per nf): col -> (oy,ox) clamped
    int oyl[8], oxl[8];
#pragma unroll
    for (int nf = 0; nf < 8; ++nf) {
        int c = waveN * 128 + nf * 16 + rl;
        int p = n0 + c; if (p > CC_NP - 1) p = CC_NP - 1;
        if (c > 247) { p = n0 + 247; if (p > CC_NP - 1) p = CC_NP - 1; }
        const int oy = p / 62;
        oyl[nf] = oy - y0;                        // 0..5 relative input row
        oxl[nf] = p - 62 * oy;
    }

    // prologue queue: [Bres(0):12, A(0):4, A(1):4] -> open(0) vmcnt(4)
    stageB(0);
    stageA(0);
    stageA(1);

#pragma unroll
    for (int t = 0; t < CC_NT; ++t) {
        const int h = t / 9, t9 = t - 9 * h;
        const int ky = t9 / 3, kx = t9 - 3 * ky;
        const char* Ab = smem + (t & 1) * 16384;

        // ---- open: A(t)+Bres ready; A(t+1) (4 loads) stays in flight
        if (t < CC_NT - 1) asm volatile("s_waitcnt vmcnt(4)" ::: "memory");
        else               asm volatile("s_waitcnt vmcnt(0)" ::: "memory");
        asm volatile("s_barrier" ::: "memory");

        // ---- frag reads + MFMA burst (compiler-scheduled lgkmcnt)
        bf16x8 af[8], bf[16];
#pragma unroll
        for (int mf = 0; mf < 4; ++mf)
#pragma unroll
            for (int kk = 0; kk < 2; ++kk) {
                const int r = waveM * 64 + mf * 16 + rl;
                af[mf * 2 + kk] = *(const bf16x8*)(Ab + r * 128 + (((kk * 4 + q) ^ (r & 7)) * 16));
            }
#pragma unroll
        for (int nf = 0; nf < 8; ++nf) {
            const int x = oxl[nf] + kx;
            const int row = (oyl[nf] + ky) * 64 + x;
#pragma unroll
            for (int kk = 0; kk < 2; ++kk)
                bf[nf * 2 + kk] = *(const bf16x8*)(Bres + row * 128 + (((kk * 4 + q) ^ (x & 7)) * 16));
        }
        __builtin_amdgcn_s_setprio(1);
#pragma unroll
        for (int kk = 0; kk < 2; ++kk)
#pragma unroll
            for (int mf = 0; mf < 4; ++mf)
#pragma unroll
                for (int nf = 0; nf < 8; ++nf)
                    acc[mf][nf] = __builtin_amdgcn_mfma_f32_16x16x32_bf16(
                        af[mf * 2 + kk], bf[nf * 2 + kk], acc[mf][nf], 0, 0, 0);
        __builtin_amdgcn_s_setprio(0);

        // ---- close: all LDS reads of this iter done before overwrites
        asm volatile("s_waitcnt lgkmcnt(0)" ::: "memory");
        asm volatile("s_barrier" ::: "memory");
        if (t == 8) stageB(1);                   // before A(t+2): vmcnt(4) still retires it
        if (t + 2 < CC_NT) stageA(t + 2);
    }

    // epilogue: C/D map col=lane&15 (p), row=(lane>>4)*4+j (cout)
    const int q4 = (lane >> 4) * 4;
#pragma unroll
    for (int mf = 0; mf < 4; ++mf) {
        const int crow = m0 + waveM * 64 + mf * 16 + q4;
#pragma unroll
        for (int nf = 0; nf < 8; ++nf) {
            const int c = waveN * 128 + nf * 16 + (lane & 15);
            const int p = n0 + c;
            if (c < 248 && p < CC_NP) {
                const size_t ob = ((size_t)b * CC_COUT + crow) * CC_NP + p;
#pragma unroll
                for (int j = 0; j < 4; ++j) out[ob + (size_t)j * CC_NP] = acc[mf][nf][j];
            }
        }
    }
}

// ---------------------------------------------------------------- launch ----
extern "C" void kernel_launch(void* const* d_in, const int* in_sizes, int n_in,
                              void* d_out, int out_size, void* d_ws, size_t ws_size,
                              hipStream_t stream) {
    const float* x   = (const float*)d_in[0];
    const float* ew  = (const float*)d_in[1];
    const float* rww = (const float*)d_in[2];
    const float* rwb = (const float*)d_in[3];
    float* out = (float*)d_out;
    char* ws = (char*)d_ws;

    __hip_bfloat16* xnhwc = (__hip_bfloat16*)ws;                    // 33,554,432 B
    __hip_bfloat16* cwcmb = (__hip_bfloat16*)(ws + 33554432);       // 18,874,368 B
    float* psum   = (float*)(ws + 52428800);                        //  1,048,576 B
    float* rwts   = (float*)(ws + 53493760);                        //      1,024 B

    cc_nhwc<<<dim3(CC_B * 64), dim3(256), 0, stream>>>(x, xnhwc, psum);
    cc_route<<<dim3(CC_B), dim3(128), 0, stream>>>(psum, rww, rwb, rwts);
    cc_combine<<<dim3(9 * CC_COUT), dim3(128), 0, stream>>>(ew, rwts, cwcmb);
    cc_conv<<<dim3(1024), dim3(256), 0, stream>>>(xnhwc, cwcmb, out);
}

// Round 11
// 112.949 us; speedup vs baseline: 1.6527x; 1.6527x over previous
//
#include <hip/hip_runtime.h>
#include <hip/hip_bf16.h>

// CondConv: B=32, CIN=128, COUT=256, K=3, E=8, H=W=64 -> out [32,256,62,62] fp32
// Pipeline: nhwc(+pool partials) -> route -> combine(bf16 cw) -> implicit-GEMM
//           MFMA conv (R6 geometry + resident-B): block 128x160, 4 waves
//           (2Mx2N, per-wave 64x80: acc[4][5]=80 VGPR, NO spill), B resident
//           in LDS per cin-half (48KB = 6 input rows, restaged at h-flip),
//           A streamed dbuf 16KB/iter, 2 blocks/CU, counted vmcnt, full unroll.

#define CC_B    32
#define CC_CIN  128
#define CC_COUT 256
#define CC_NP   3844   // 62*62
#define CC_NT   18     // t = h*9 + t9 : h = cin-half (64), t9 = tap

typedef __attribute__((ext_vector_type(8))) short bf16x8;
typedef __attribute__((ext_vector_type(4))) float f32x4;

// ------------------------------------------------- NHWC cast + pool partials
__global__ void cc_nhwc(const float* __restrict__ x, __hip_bfloat16* __restrict__ xn,
                        float* __restrict__ psum) {
    const int b = blockIdx.x >> 6, y = blockIdx.x & 63;   // 2048 blocks
    __shared__ float lds[64 * 129];                        // [x][cin], +1 pad
    __shared__ float sred[256];
    const int t = threadIdx.x;                             // 256
    const float* src = x + (size_t)b * CC_CIN * 4096 + y * 64;
#pragma unroll
    for (int i = 0; i < 32; ++i) {
        const int idx = i * 256 + t;
        const int cin = idx >> 6, xx = idx & 63;
        lds[xx * 129 + cin] = src[(size_t)cin * 4096 + xx];
    }
    __syncthreads();
    __hip_bfloat16* dst = xn + ((size_t)b * 4096 + y * 64) * CC_CIN;
#pragma unroll
    for (int j = 0; j < 4; ++j) {
        const int cidx = j * 256 + t;                      // 1024 chunks of 8 cin
        const int xx = cidx >> 4, c8 = (cidx & 15) * 8;
        union { __hip_bfloat16 h[8]; uint4 v; } u;
#pragma unroll
        for (int jj = 0; jj < 8; ++jj) u.h[jj] = __float2bfloat16(lds[xx * 129 + c8 + jj]);
        *reinterpret_cast<uint4*>(dst + (size_t)xx * CC_CIN + c8) = u.v;
    }
    const int cin = t & 127, xh = (t >> 7) * 32;
    float s = 0.f;
#pragma unroll
    for (int xx = 0; xx < 32; ++xx) s += lds[(xh + xx) * 129 + cin];
    sred[t] = s;
    __syncthreads();
    if (t < 128) psum[((size_t)b * 64 + y) * CC_CIN + t] = sred[t] + sred[t + 128];
}

// ------------------------------------------------- route: reduce + softmax --
__global__ void cc_route(const float* __restrict__ psum,
                         const float* __restrict__ rw_w,
                         const float* __restrict__ rw_b,
                         float* __restrict__ rweights) {
    const int b = blockIdx.x, c = threadIdx.x;             // 32 blocks x 128
    __shared__ float pl[128];
    __shared__ float lg[8];
    const float* p = psum + (size_t)b * 64 * CC_CIN + c;
    float s = 0.f;
#pragma unroll 8
    for (int y = 0; y < 64; ++y) s += p[(size_t)y * CC_CIN];
    pl[c] = s * (1.f / 4096.f);
    __syncthreads();
    if (c < 8) {
        const float* w = rw_w + c * CC_CIN;
        float a = rw_b[c];
#pragma unroll 8
        for (int i = 0; i < CC_CIN; ++i) a += pl[i] * w[i];
        lg[c] = a;
    }
    __syncthreads();
    if (c == 0) {
        float m = lg[0];
#pragma unroll
        for (int e = 1; e < 8; ++e) m = fmaxf(m, lg[e]);
        float ex[8], sm = 0.f;
#pragma unroll
        for (int e = 0; e < 8; ++e) { ex[e] = __expf(lg[e] - m); sm += ex[e]; }
#pragma unroll
        for (int e = 0; e < 8; ++e) rweights[b * 8 + e] = ex[e] / sm;
    }
}

// -------------------------------------------------------------- combine -----
__global__ void cc_combine(const float* __restrict__ ew,
                           const float* __restrict__ rw,
                           __hip_bfloat16* __restrict__ cw) {
    const int t9 = blockIdx.x >> 8;            // 0..8
    const int cout = blockIdx.x & 255;
    const int cin = threadIdx.x;               // 128 threads
    __shared__ float rws[256];
    rws[cin] = rw[cin];
    rws[cin + 128] = rw[cin + 128];
    __syncthreads();
    float wv[8];
    const size_t base = ((size_t)cout * CC_CIN + cin) * 9 + t9;
#pragma unroll
    for (int e = 0; e < 8; ++e) wv[e] = ew[base + (size_t)e * (CC_COUT * CC_CIN * 9)];
#pragma unroll 4
    for (int b = 0; b < CC_B; ++b) {
        float acc = 0.f;
#pragma unroll
        for (int e = 0; e < 8; ++e) acc += rws[b * 8 + e] * wv[e];
        cw[(((size_t)b * 9 + t9) * CC_COUT + cout) * CC_CIN + cin] = __float2bfloat16(acc);
    }
}

// ----------------------------------------------------------------- conv -----
__device__ __forceinline__ void gload_lds16(const void* g, void* l) {
    __builtin_amdgcn_global_load_lds(
        (const __attribute__((address_space(1))) unsigned int*)g,
        (__attribute__((address_space(3))) unsigned int*)l, 16, 0, 0);
}

// grid 1600, block 256 (4 waves, 2M x 2N). Tile BM=128 x BN=160, per-wave
// 64x80 (acc[4][5]). LDS 80KB: A dbuf 2x16KB @0; Bres 48KB @32768 =
// [row=yy*64+x][64cin] for 6 input rows y0..y0+5, staged once per cin-half
// (restage at t=8 close). 2 blocks/CU.
// Ledger: prologue [B(0):12, A(0):4, A(1):4]; open(t) = vmcnt(4)+barrier
// (waitcnt BEFORE barrier -> cross-wave quarters safe); close = lgkm0+barrier;
// close(8): stageB(1) then stageA(10) -> open(9) vmcnt(4) drains B(1).
// Swizzle: LDS slot s of 128B row r holds source chunk s^(r&7); Bres rows
// have row&7 == x&7, so B-read XOR key is (x&7). A as in R6 (key r&7).
__global__ __launch_bounds__(256, 2) void cc_conv(
    const __hip_bfloat16* __restrict__ xn,   // [B][64][64][128]
    const __hip_bfloat16* __restrict__ cw,   // [B][9][256][128]
    float* __restrict__ out)                 // [B][256][3844]
{
    __shared__ __align__(16) char smem[81920];
    // ---- XCD-aware decode (bijective over 1600 = 8 xcd x 4 b x 25 nt x 2 mt)
    const int l   = blockIdx.x;
    const int xcd = l & 7, li = l >> 3;          // li in [0,200)
    const int b   = 4 * xcd + li / 50;
    const int r2  = li % 50;
    const int nt  = r2 >> 1, mt = r2 & 1;
    const int m0  = mt * 128;
    const int n0  = nt * 160;                    // 640B-aligned stores
    const int y0  = n0 / 62;                     // first output row touched

    const int tid = threadIdx.x;
    const int wid = tid >> 6, lane = tid & 63;   // wid 0..3
    const int waveM = wid >> 1, waveN = wid & 1;

    f32x4 acc[4][5];
#pragma unroll
    for (int i = 0; i < 4; ++i)
#pragma unroll
        for (int j = 0; j < 5; ++j) acc[i][j] = (f32x4){0.f, 0.f, 0.f, 0.f};

    const int gsw = (lane & 7) ^ (lane >> 3);    // staging source-chunk swizzle
    const __hip_bfloat16* cwb = cw + (size_t)b * 9 * CC_COUT * CC_CIN;
    const __hip_bfloat16* xnb = xn + (size_t)b * 4096 * CC_CIN;

    // ---- A staging (4 issues/wave, rows wid*32+i*8+(l>>3))
    int laOff[4];
#pragma unroll
    for (int i = 0; i < 4; ++i) {
        const int row = wid * 32 + i * 8 + (lane >> 3);
        laOff[i] = (m0 + row) * CC_CIN + gsw * 8;
    }
    auto stageA = [&](int t) {
        const int h = t / 9, t9 = t - 9 * h;
        const int aoff = t9 * (CC_COUT * CC_CIN) + h * 64;
        char* Ab = smem + (t & 1) * 16384 + wid * 4096;
#pragma unroll
        for (int i = 0; i < 4; ++i)
            gload_lds16(cwb + aoff + laOff[i], Ab + i * 1024);
    };

    // ---- Bres staging: 48KB = 384 rows x 128B; 12 issues/wave, wid-partitioned.
    // row = i*32 + wid*8 + (lane>>3); yy=row>>6, x=row&63; row&7 == lane>>3.
    char* Bres = smem + 32768;
    auto stageB = [&](int h) {
#pragma unroll
        for (int i = 0; i < 12; ++i) {
            const int row = i * 32 + wid * 8 + (lane >> 3);
            const int yy = row >> 6, x = row & 63;
            int yin = y0 + yy; if (yin > 63) yin = 63;
            gload_lds16(xnb + ((size_t)yin * 64 + x) * CC_CIN + h * 64 + gsw * 8,
                        Bres + i * 4096 + wid * 1024);
        }
    };

    const int rl = lane & 15, q = lane >> 4;

    // per-lane B position decode (per nf): p -> (rel row, x-base)
    int oyl[5], oxl[5];
#pragma unroll
    for (int nf = 0; nf < 5; ++nf) {
        int p = n0 + waveN * 80 + nf * 16 + rl;
        if (p > CC_NP - 1) p = CC_NP - 1;        // last-tile clamp (store-masked)
        const int oy = p / 62;
        oyl[nf] = oy - y0;                        // 0..3
        oxl[nf] = p - 62 * oy;                    // 0..61
    }

    // prologue queue: [Bres(0):12, A(0):4, A(1):4]
    stageB(0);
    stageA(0);
    stageA(1);

#pragma unroll
    for (int t = 0; t < CC_NT; ++t) {
        const int h = t / 9, t9 = t - 9 * h;
        const int ky = t9 / 3, kx = t9 - 3 * ky;
        const char* Ab = smem + (t & 1) * 16384;

        // ---- open: own A(t)+Bres(h) retired; A(t+1) stays in flight
        if (t < CC_NT - 1) asm volatile("s_waitcnt vmcnt(4)" ::: "memory");
        else               asm volatile("s_waitcnt vmcnt(0)" ::: "memory");
        asm volatile("s_barrier" ::: "memory");

        // ---- frag reads + MFMA burst (compiler-scheduled lgkmcnt)
        bf16x8 af[8], bf[10];
#pragma unroll
        for (int mf = 0; mf < 4; ++mf)
#pragma unroll
            for (int kk = 0; kk < 2; ++kk) {
                const int r = waveM * 64 + mf * 16 + rl;
                af[mf * 2 + kk] = *(const bf16x8*)(Ab + r * 128 + (((kk * 4 + q) ^ (r & 7)) * 16));
            }
#pragma unroll
        for (int nf = 0; nf < 5; ++nf) {
            const int x = oxl[nf] + kx;                    // 0..63, no wrap
            const int row = (oyl[nf] + ky) * 64 + x;       // < 384
#pragma unroll
            for (int kk = 0; kk < 2; ++kk)
                bf[nf * 2 + kk] = *(const bf16x8*)(Bres + row * 128 + (((kk * 4 + q) ^ (x & 7)) * 16));
        }
        __builtin_amdgcn_s_setprio(1);
#pragma unroll
        for (int kk = 0; kk < 2; ++kk)
#pragma unroll
            for (int mf = 0; mf < 4; ++mf)
#pragma unroll
                for (int nf = 0; nf < 5; ++nf)
                    acc[mf][nf] = __builtin_amdgcn_mfma_f32_16x16x32_bf16(
                        af[mf * 2 + kk], bf[nf * 2 + kk], acc[mf][nf], 0, 0, 0);
        __builtin_amdgcn_s_setprio(0);

        // ---- close: all LDS reads done before any restage overwrites
        asm volatile("s_waitcnt lgkmcnt(0)" ::: "memory");
        asm volatile("s_barrier" ::: "memory");
        if (t == 8) stageB(1);                   // before A(10): vmcnt(4) drains it
        if (t + 2 < CC_NT) stageA(t + 2);
    }

    // epilogue: C/D map col=lane&15 (p), row=(lane>>4)*4+j (cout)
    const int q4 = (lane >> 4) * 4;
#pragma unroll
    for (int mf = 0; mf < 4; ++mf) {
        const int crow = m0 + waveM * 64 + mf * 16 + q4;
#pragma unroll
        for (int nf = 0; nf < 5; ++nf) {
            const int p = n0 + waveN * 80 + nf * 16 + (lane & 15);
            if (p < CC_NP) {
                const size_t ob = ((size_t)b * CC_COUT + crow) * CC_NP + p;
#pragma unroll
                for (int j = 0; j < 4; ++j) out[ob + (size_t)j * CC_NP] = acc[mf][nf][j];
            }
        }
    }
}

// ---------------------------------------------------------------- launch ----
extern "C" void kernel_launch(void* const* d_in, const int* in_sizes, int n_in,
                              void* d_out, int out_size, void* d_ws, size_t ws_size,
                              hipStream_t stream) {
    const float* x   = (const float*)d_in[0];
    const float* ew  = (const float*)d_in[1];
    const float* rww = (const float*)d_in[2];
    const float* rwb = (const float*)d_in[3];
    float* out = (float*)d_out;
    char* ws = (char*)d_ws;

    __hip_bfloat16* xnhwc = (__hip_bfloat16*)ws;                    // 33,554,432 B
    __hip_bfloat16* cwcmb = (__hip_bfloat16*)(ws + 33554432);       // 18,874,368 B
    float* psum   = (float*)(ws + 52428800);                        //  1,048,576 B
    float* rwts   = (float*)(ws + 53493760);                        //      1,024 B

    cc_nhwc<<<dim3(CC_B * 64), dim3(256), 0, stream>>>(x, xnhwc, psum);
    cc_route<<<dim3(CC_B), dim3(128), 0, stream>>>(psum, rww, rwb, rwts);
    cc_combine<<<dim3(9 * CC_COUT), dim3(128), 0, stream>>>(ew, rwts, cwcmb);
    cc_conv<<<dim3(1600), dim3(256), 0, stream>>>(xnhwc, cwcmb, out);
}